// Round 3
// baseline (189.501 us; speedup 1.0000x reference)
//
#include <hip/hip_runtime.h>
#include <stdint.h>

typedef __bf16 bf16;
typedef __attribute__((ext_vector_type(8))) __bf16 bf16x8;
typedef __attribute__((ext_vector_type(4))) __bf16 bf16x4;
typedef __attribute__((ext_vector_type(4))) float  f32x4;

#define ATT_SCALE 0.125f   // 1/sqrt(64), folded into Q at GEMM epilogue

// ---------------------------------------------------------------------------
// async 16B global -> LDS (wave-uniform LDS base + lane*16, per-lane gaddr)
// ---------------------------------------------------------------------------
__device__ __forceinline__ void async16(void* lds, const void* g) {
  __builtin_amdgcn_global_load_lds(
      (__attribute__((address_space(1))) void*)(void*)g,
      (__attribute__((address_space(3))) void*)lds,
      16, 0, 0);
}

// ---------------------------------------------------------------------------
// fp32 -> bf16 convert, 8 elems/thread
// ---------------------------------------------------------------------------
__global__ void convert_x_kernel(const float* __restrict__ x, bf16* __restrict__ y) {
  size_t i = ((size_t)blockIdx.x * 256 + threadIdx.x) * 8;
  float4 a = *(const float4*)(x + i);
  float4 b = *(const float4*)(x + i + 4);
  bf16x8 o;
  o[0] = (bf16)a.x; o[1] = (bf16)a.y; o[2] = (bf16)a.z; o[3] = (bf16)a.w;
  o[4] = (bf16)b.x; o[5] = (bf16)b.y; o[6] = (bf16)b.z; o[7] = (bf16)b.w;
  *(bf16x8*)(y + i) = o;
}

// ---------------------------------------------------------------------------
// W [768 x 2304] fp32  ->  Wt [2304 x 768] bf16  (LDS tiled transpose)
// ---------------------------------------------------------------------------
__global__ void transpose_w_kernel(const float* __restrict__ W, bf16* __restrict__ Wt) {
  __shared__ float tile[32][33];
  int tx = threadIdx.x, ty = threadIdx.y;
  int n0 = blockIdx.x * 32, k0 = blockIdx.y * 32;
#pragma unroll
  for (int r = 0; r < 4; ++r)
    tile[ty + r * 8][tx] = W[(size_t)(k0 + ty + r * 8) * 2304 + n0 + tx];
  __syncthreads();
#pragma unroll
  for (int r = 0; r < 4; ++r)
    Wt[(size_t)(n0 + ty + r * 8) * 768 + k0 + tx] = (bf16)tile[tx][ty + r * 8];
}

// ---------------------------------------------------------------------------
// QKV GEMM: C[8192 x 2304] = A[8192 x 768] * W + bias
//   128x128 tile, BK=32, double-buffered LDS, ONE barrier per K-iter.
//   DMA prefetch for iter k+1 issues right after the barrier -> at the next
//   barrier's vmcnt(0) drain those loads are a full compute-phase old.
//   Epilogue: +bias, Q pre-scaled by 1/sqrt(64), ->bf16,
//   Q[bh][t][64], K[bh][t][64], V^T[bh][64][t].
// ---------------------------------------------------------------------------
__global__ void qkv_gemm_kernel(const bf16* __restrict__ A, const bf16* __restrict__ Bw,
                                const float* __restrict__ bias,
                                bf16* __restrict__ Qo, bf16* __restrict__ Ko,
                                bf16* __restrict__ Vo) {
  __shared__ __align__(16) char lds[33024];   // 2 x (A 8256 + B 8256)

  const int tid  = threadIdx.x;
  const int wave = tid >> 6, lane = tid & 63;
  const int quad = lane >> 4, mn = lane & 15;
  const int wr = wave >> 1, wc = wave & 1;
  const int m0 = blockIdx.y * 128;
  const int n0 = blockIdx.x * 128;

  f32x4 acc[4][4] = {};
  const int kb = wave;  // each wave DMAs one k-block (8 k) of both tiles

  auto stage = [&](int kt, char* buf) {
    char* Al = buf;
    char* Bl = buf + 8256;
#pragma unroll
    for (int half = 0; half < 2; ++half) {
      async16(Al + kb * 2064 + half * 1024,
              A + (size_t)(m0 + half * 64 + lane) * 768 + kt + kb * 8);
      async16(Bl + kb * 2064 + half * 1024,
              Bw + (size_t)(n0 + half * 64 + lane) * 768 + kt + kb * 8);
    }
  };

  stage(0, lds);
  int p = 0;
  for (int kt = 0; kt < 768; kt += 32) {
    __syncthreads();                              // drains DMA into buf p
    if (kt + 32 < 768) stage(kt + 32, lds + (p ^ 1) * 16512);  // prefetch
    char* Al = lds + p * 16512;
    char* Bl = Al + 8256;

    bf16x8 af[4], bfr[4];
#pragma unroll
    for (int i = 0; i < 4; ++i) {
      af[i]  = *(const bf16x8*)(Al + quad * 2064 + (wr * 64 + i * 16 + mn) * 16);
      bfr[i] = *(const bf16x8*)(Bl + quad * 2064 + (wc * 64 + i * 16 + mn) * 16);
    }
#pragma unroll
    for (int i = 0; i < 4; ++i)
#pragma unroll
      for (int j = 0; j < 4; ++j)
        acc[i][j] = __builtin_amdgcn_mfma_f32_16x16x32_bf16(af[i], bfr[j], acc[i][j], 0, 0, 0);
    p ^= 1;
  }

  // epilogue
  const int ng    = n0 + wc * 64;
  const int third = ng / 768;           // 0=Q 1=K 2=V
  const int nmod  = ng % 768;
  const float sc  = (third == 0) ? ATT_SCALE : 1.0f;
#pragma unroll
  for (int ct = 0; ct < 4; ++ct) {
    int n = nmod + ct * 16 + mn;
    int h = n >> 6, d = n & 63;
    float bv = bias[third * 768 + n];
#pragma unroll
    for (int rt = 0; rt < 4; ++rt) {
      int m  = m0 + wr * 64 + rt * 16 + quad * 4;
      int b  = m >> 10, t0 = m & 1023;
      size_t bh = (size_t)b * 12 + h;
      if (third == 2) {
        bf16x4 pk;
#pragma unroll
        for (int r = 0; r < 4; ++r) pk[r] = (bf16)(acc[rt][ct][r] + bv);
        *(bf16x4*)(Vo + (bh * 64 + d) * 1024 + t0) = pk;   // V^T
      } else {
        bf16* dst = (third == 0 ? Qo : Ko) + (bh * 1024 + t0) * 64 + d;
#pragma unroll
        for (int r = 0; r < 4; ++r) dst[(size_t)r * 64] = (bf16)((acc[rt][ct][r] + bv) * sc);
      }
    }
  }
}

// ---------------------------------------------------------------------------
// Attention: block = (bh, 128-row Q tile). 4 waves x 32 q-rows.
//   KV tiles (64 wide) double-buffered in LDS; global loads for j+1 issued
//   one iteration ahead; ONE barrier per iter. S LDS rows are wave-private
//   (no barrier for the C-layout -> A-layout round trip). Per-wave causal
//   skip: wave w's diagonal tile jdiag = 2*qt + (w>>1); j>jdiag fully masked.
// ---------------------------------------------------------------------------
__global__ void attn_kernel(const bf16* __restrict__ Q, const bf16* __restrict__ K,
                            const bf16* __restrict__ Vt, float* __restrict__ out) {
  __shared__ __align__(16) char lds[55296];
  // buf p: ldsK = lds + p*18432, ldsV = ldsK + 9216   (64 rows x 144B)
  char* ldsS = lds + 36864;                            // 128 rows x 144B

  const int tid  = threadIdx.x;
  const int wave = tid >> 6, lane = tid & 63;
  const int quad = lane >> 4, mn = lane & 15;
  const int bh = blockIdx.x;
  const int qt = (int)gridDim.y - 1 - (int)blockIdx.y;   // heavy tiles first
  const int q0 = qt * 128;
  const int jmax  = 2 * qt + 1;
  const int jdiag = 2 * qt + (wave >> 1);

  // Q fragments (A operand), rows q0 + wave*32 + i*16 + mn
  const bf16* Qbase = Q + ((size_t)bh * 1024 + q0 + wave * 32) * 64;
  bf16x8 qf[2][2];
#pragma unroll
  for (int i = 0; i < 2; ++i) {
    const bf16* Qrow = Qbase + (i * 16 + mn) * 64;
    qf[i][0] = *(const bf16x8*)(Qrow + quad * 8);
    qf[i][1] = *(const bf16x8*)(Qrow + 32 + quad * 8);
  }

  f32x4 yacc[2][4] = {};

  const int trow = tid >> 3;     // 0..31
  const int tcol = tid & 7;      // 0..7
  const bf16* Kg0 = K  + (size_t)bh * 65536;
  const bf16* Vg0 = Vt + (size_t)bh * 65536;

  // prologue: stage tile j=0 into regs
  bf16x8 r0 = *(const bf16x8*)(Kg0 + trow * 64 + tcol * 8);
  bf16x8 r1 = *(const bf16x8*)(Kg0 + (trow + 32) * 64 + tcol * 8);
  bf16x8 r2 = *(const bf16x8*)(Vg0 + (size_t)trow * 1024 + tcol * 8);
  bf16x8 r3 = *(const bf16x8*)(Vg0 + (size_t)(trow + 32) * 1024 + tcol * 8);

  for (int j = 0; j <= jmax; ++j) {
    char* bK = lds + (j & 1) * 18432;
    char* bV = bK + 9216;
    *(bf16x8*)(bK + trow * 144 + tcol * 16) = r0;
    *(bf16x8*)(bK + (trow + 32) * 144 + tcol * 16) = r1;
    *(bf16x8*)(bV + trow * 144 + tcol * 16) = r2;
    *(bf16x8*)(bV + (trow + 32) * 144 + tcol * 16) = r3;
    if (j < jmax) {   // prefetch next KV tile into regs (overlaps compute)
      const bf16* Kg = Kg0 + (size_t)(j + 1) * 4096;
      const bf16* Vg = Vg0 + (j + 1) * 64;
      r0 = *(const bf16x8*)(Kg + trow * 64 + tcol * 8);
      r1 = *(const bf16x8*)(Kg + (trow + 32) * 64 + tcol * 8);
      r2 = *(const bf16x8*)(Vg + (size_t)trow * 1024 + tcol * 8);
      r3 = *(const bf16x8*)(Vg + (size_t)(trow + 32) * 1024 + tcol * 8);
    }
    __syncthreads();

    if (j <= jdiag) {
      const bool diag = (j == jdiag);
      // S = relu(mask(Q K^T)) -> bf16 in LDS (wave-private rows)
#pragma unroll
      for (int ct = 0; ct < 4; ++ct) {
        bf16x8 kf0 = *(const bf16x8*)(bK + (ct * 16 + mn) * 144 + quad * 16);
        bf16x8 kf1 = *(const bf16x8*)(bK + (ct * 16 + mn) * 144 + 64 + quad * 16);
        int kkc = j * 64 + ct * 16 + mn;
#pragma unroll
        for (int i = 0; i < 2; ++i) {
          f32x4 a = {};
          a = __builtin_amdgcn_mfma_f32_16x16x32_bf16(qf[i][0], kf0, a, 0, 0, 0);
          a = __builtin_amdgcn_mfma_f32_16x16x32_bf16(qf[i][1], kf1, a, 0, 0, 0);
          int qr = q0 + wave * 32 + i * 16 + quad * 4;
#pragma unroll
          for (int r = 0; r < 4; ++r) {
            float v = a[r];
            v = v > 0.f ? v : 0.f;
            if (diag && kkc > qr + r) v = 0.f;
            ((bf16*)ldsS)[(wave * 32 + i * 16 + quad * 4 + r) * 72 + ct * 16 + mn] = (bf16)v;
          }
        }
      }
      // Y += S * V
#pragma unroll
      for (int kb = 0; kb < 2; ++kb) {
        bf16x8 vf[4];
#pragma unroll
        for (int ct = 0; ct < 4; ++ct)
          vf[ct] = *(const bf16x8*)(bV + (ct * 16 + mn) * 144 + kb * 64 + quad * 16);
#pragma unroll
        for (int i = 0; i < 2; ++i) {
          bf16x8 sf = *(const bf16x8*)(ldsS + (wave * 32 + i * 16 + mn) * 144 + kb * 64 + quad * 16);
#pragma unroll
          for (int ct = 0; ct < 4; ++ct)
            yacc[i][ct] = __builtin_amdgcn_mfma_f32_16x16x32_bf16(sf, vf[ct], yacc[i][ct], 0, 0, 0);
        }
      }
    }
  }

  // write out: out[b][t][h*64+d]
  const int b = bh / 12, h = bh % 12;
#pragma unroll
  for (int i = 0; i < 2; ++i) {
    float* ob = out + ((size_t)b * 1024 + q0 + wave * 32 + i * 16 + quad * 4) * 768 + h * 64;
#pragma unroll
    for (int ct = 0; ct < 4; ++ct)
#pragma unroll
      for (int r = 0; r < 4; ++r)
        ob[(size_t)r * 768 + ct * 16 + mn] = yacc[i][ct][r];
  }
}

// ---------------------------------------------------------------------------
extern "C" void kernel_launch(void* const* d_in, const int* in_sizes, int n_in,
                              void* d_out, int out_size, void* d_ws, size_t ws_size,
                              hipStream_t stream) {
  const float* x    = (const float*)d_in[0];   // [8,1024,768]
  const float* W    = (const float*)d_in[1];   // [768,2304]
  const float* bias = (const float*)d_in[2];   // [2304]
  float* out = (float*)d_out;                  // [8,1024,768]

  char* ws = (char*)d_ws;
  bf16* xb = (bf16*)(ws);                      // 8192*768        = 12,582,912 B
  bf16* Wt = (bf16*)(ws + 12582912);           // 2304*768        =  3,538,944 B
  bf16* Qb = (bf16*)(ws + 16121856);           // 96*1024*64
  bf16* Kb = (bf16*)(ws + 28704768);           // 96*1024*64
  bf16* Vb = (bf16*)(ws + 41287680);           // 96*64*1024 (V^T)

  convert_x_kernel<<<3072, 256, 0, stream>>>(x, xb);
  transpose_w_kernel<<<dim3(72, 24), dim3(32, 8), 0, stream>>>(W, Wt);
  qkv_gemm_kernel<<<dim3(18, 64), 256, 0, stream>>>(xb, Wt, bias, Qb, Kb, Vb);
  attn_kernel<<<dim3(96, 8), 256, 0, stream>>>(Qb, Kb, Vb, out);
}

// Round 4
// 151.403 us; speedup vs baseline: 1.2516x; 1.2516x over previous
//
#include <hip/hip_runtime.h>
#include <stdint.h>

typedef __bf16 bf16;
typedef __attribute__((ext_vector_type(8))) __bf16 bf16x8;
typedef __attribute__((ext_vector_type(4))) __bf16 bf16x4;
typedef __attribute__((ext_vector_type(4))) float  f32x4;

#define ATT_SCALE 0.125f   // 1/sqrt(64), folded into Q at GEMM epilogue

// ---------------------------------------------------------------------------
// async 16B global -> LDS (wave-uniform LDS base + lane*16, per-lane gaddr)
// ---------------------------------------------------------------------------
__device__ __forceinline__ void async16(void* lds, const void* g) {
  __builtin_amdgcn_global_load_lds(
      (__attribute__((address_space(1))) void*)(void*)g,
      (__attribute__((address_space(3))) void*)lds,
      16, 0, 0);
}

// ---------------------------------------------------------------------------
// fp32 -> bf16 convert, 8 elems/thread
// ---------------------------------------------------------------------------
__global__ void convert_x_kernel(const float* __restrict__ x, bf16* __restrict__ y) {
  size_t i = ((size_t)blockIdx.x * 256 + threadIdx.x) * 8;
  float4 a = *(const float4*)(x + i);
  float4 b = *(const float4*)(x + i + 4);
  bf16x8 o;
  o[0] = (bf16)a.x; o[1] = (bf16)a.y; o[2] = (bf16)a.z; o[3] = (bf16)a.w;
  o[4] = (bf16)b.x; o[5] = (bf16)b.y; o[6] = (bf16)b.z; o[7] = (bf16)b.w;
  *(bf16x8*)(y + i) = o;
}

// ---------------------------------------------------------------------------
// W [768 x 2304] fp32  ->  Wt [2304 x 768] bf16  (LDS tiled transpose)
// ---------------------------------------------------------------------------
__global__ void transpose_w_kernel(const float* __restrict__ W, bf16* __restrict__ Wt) {
  __shared__ float tile[32][33];
  int tx = threadIdx.x, ty = threadIdx.y;
  int n0 = blockIdx.x * 32, k0 = blockIdx.y * 32;
#pragma unroll
  for (int r = 0; r < 4; ++r)
    tile[ty + r * 8][tx] = W[(size_t)(k0 + ty + r * 8) * 2304 + n0 + tx];
  __syncthreads();
#pragma unroll
  for (int r = 0; r < 4; ++r)
    Wt[(size_t)(n0 + ty + r * 8) * 768 + k0 + tx] = (bf16)tile[tx][ty + r * 8];
}

// ---------------------------------------------------------------------------
// QKV GEMM: C[8192 x 2304] = A[8192 x 768] * Wt^T + bias
//   Tile 128x128, BK=64, single-buffered LDS (32KB), m97 2-barrier K-loop.
//   STAGING IS LINE-COALESCED: each DMA instr covers 8 rows x 128B, each row
//   chunk being exactly one aligned 128B line (8 lanes/row). The lane->chunk
//   mapping bakes in an XOR swizzle (stored chunk = global chunk ^ (row&7)),
//   so fragment ds_read_b128s are 2-way (free) instead of 8-way.
//   Per wave-iter: 8 DMA + 16 ds_read_b128 + 32 MFMA. 12 iters.
//   Epilogue: +bias, Q pre-scaled by 1/sqrt(64), ->bf16,
//   Q[bh][t][64], K[bh][t][64], V^T[bh][64][t].
// ---------------------------------------------------------------------------
__global__ void qkv_gemm_kernel(const bf16* __restrict__ A, const bf16* __restrict__ Bw,
                                const float* __restrict__ bias,
                                bf16* __restrict__ Qo, bf16* __restrict__ Ko,
                                bf16* __restrict__ Vo) {
  __shared__ __align__(16) char lds[32768];   // A 16KB + B 16KB
  char* Al = lds;
  char* Bl = lds + 16384;

  const int tid  = threadIdx.x;
  const int wave = tid >> 6, lane = tid & 63;
  const int quad = lane >> 4, mn = lane & 15;
  const int wr = wave >> 1, wc = wave & 1;
  const int m0 = blockIdx.y * 128;
  const int n0 = blockIdx.x * 128;

  f32x4 acc[4][4] = {};

  const int lrow = lane >> 3;           // 0..7  (row within 8-row group)
  const int cg   = (lane & 7) ^ lrow;   // global 16B-chunk index (swizzled)

  for (int kt = 0; kt < 768; kt += 64) {
#pragma unroll
    for (int u = 0; u < 4; ++u) {
      const int t   = wave * 4 + u;      // 8-row group 0..15
      const int row = t * 8 + lrow;      // tile row 0..127
      async16(Al + t * 1024 + lane * 16,
              A  + (size_t)(m0 + row) * 768 + kt + cg * 8);
      async16(Bl + t * 1024 + lane * 16,
              Bw + (size_t)(n0 + row) * 768 + kt + cg * 8);
    }
    __syncthreads();                     // drain DMA

#pragma unroll
    for (int s = 0; s < 2; ++s) {        // two K=32 steps within BK=64
      bf16x8 af[4], bfr[4];
      const int csw = ((s * 4 + quad) ^ (mn & 7)) * 16;  // swizzled chunk offset
#pragma unroll
      for (int i = 0; i < 4; ++i) {
        af[i]  = *(const bf16x8*)(Al + (wr * 64 + i * 16 + mn) * 128 + csw);
        bfr[i] = *(const bf16x8*)(Bl + (wc * 64 + i * 16 + mn) * 128 + csw);
      }
#pragma unroll
      for (int i = 0; i < 4; ++i)
#pragma unroll
        for (int j = 0; j < 4; ++j)
          acc[i][j] = __builtin_amdgcn_mfma_f32_16x16x32_bf16(af[i], bfr[j], acc[i][j], 0, 0, 0);
    }
    __syncthreads();                     // reads done before next overwrite
  }

  // epilogue
  const int ng    = n0 + wc * 64;
  const int third = ng / 768;           // 0=Q 1=K 2=V
  const int nmod  = ng % 768;
  const float sc  = (third == 0) ? ATT_SCALE : 1.0f;
#pragma unroll
  for (int ct = 0; ct < 4; ++ct) {
    int n = nmod + ct * 16 + mn;
    int h = n >> 6, d = n & 63;
    float bv = bias[third * 768 + n];
#pragma unroll
    for (int rt = 0; rt < 4; ++rt) {
      int m  = m0 + wr * 64 + rt * 16 + quad * 4;
      int b  = m >> 10, t0 = m & 1023;
      size_t bh = (size_t)b * 12 + h;
      if (third == 2) {
        bf16x4 pk;
#pragma unroll
        for (int r = 0; r < 4; ++r) pk[r] = (bf16)(acc[rt][ct][r] + bv);
        *(bf16x4*)(Vo + (bh * 64 + d) * 1024 + t0) = pk;   // V^T
      } else {
        bf16* dst = (third == 0 ? Qo : Ko) + (bh * 1024 + t0) * 64 + d;
#pragma unroll
        for (int r = 0; r < 4; ++r) dst[(size_t)r * 64] = (bf16)((acc[rt][ct][r] + bv) * sc);
      }
    }
  }
}

// ---------------------------------------------------------------------------
// Attention: block = (bh, 128-row Q tile). 4 waves x 32 q-rows.
//   KV tiles (64 wide) double-buffered in LDS; global loads for j+1 issued
//   one iteration ahead; ONE barrier per iter. S LDS rows are wave-private
//   (no barrier for the C-layout -> A-layout round trip). Per-wave causal
//   skip: wave w's diagonal tile jdiag = 2*qt + (w>>1); j>jdiag fully masked.
// ---------------------------------------------------------------------------
__global__ void attn_kernel(const bf16* __restrict__ Q, const bf16* __restrict__ K,
                            const bf16* __restrict__ Vt, float* __restrict__ out) {
  __shared__ __align__(16) char lds[55296];
  // buf p: ldsK = lds + p*18432, ldsV = ldsK + 9216   (64 rows x 144B)
  char* ldsS = lds + 36864;                            // 128 rows x 144B

  const int tid  = threadIdx.x;
  const int wave = tid >> 6, lane = tid & 63;
  const int quad = lane >> 4, mn = lane & 15;
  const int bh = blockIdx.x;
  const int qt = (int)gridDim.y - 1 - (int)blockIdx.y;   // heavy tiles first
  const int q0 = qt * 128;
  const int jmax  = 2 * qt + 1;
  const int jdiag = 2 * qt + (wave >> 1);

  // Q fragments (A operand), rows q0 + wave*32 + i*16 + mn
  const bf16* Qbase = Q + ((size_t)bh * 1024 + q0 + wave * 32) * 64;
  bf16x8 qf[2][2];
#pragma unroll
  for (int i = 0; i < 2; ++i) {
    const bf16* Qrow = Qbase + (i * 16 + mn) * 64;
    qf[i][0] = *(const bf16x8*)(Qrow + quad * 8);
    qf[i][1] = *(const bf16x8*)(Qrow + 32 + quad * 8);
  }

  f32x4 yacc[2][4] = {};

  const int trow = tid >> 3;     // 0..31
  const int tcol = tid & 7;      // 0..7
  const bf16* Kg0 = K  + (size_t)bh * 65536;
  const bf16* Vg0 = Vt + (size_t)bh * 65536;

  // prologue: stage tile j=0 into regs
  bf16x8 r0 = *(const bf16x8*)(Kg0 + trow * 64 + tcol * 8);
  bf16x8 r1 = *(const bf16x8*)(Kg0 + (trow + 32) * 64 + tcol * 8);
  bf16x8 r2 = *(const bf16x8*)(Vg0 + (size_t)trow * 1024 + tcol * 8);
  bf16x8 r3 = *(const bf16x8*)(Vg0 + (size_t)(trow + 32) * 1024 + tcol * 8);

  for (int j = 0; j <= jmax; ++j) {
    char* bK = lds + (j & 1) * 18432;
    char* bV = bK + 9216;
    *(bf16x8*)(bK + trow * 144 + tcol * 16) = r0;
    *(bf16x8*)(bK + (trow + 32) * 144 + tcol * 16) = r1;
    *(bf16x8*)(bV + trow * 144 + tcol * 16) = r2;
    *(bf16x8*)(bV + (trow + 32) * 144 + tcol * 16) = r3;
    if (j < jmax) {   // prefetch next KV tile into regs (overlaps compute)
      const bf16* Kg = Kg0 + (size_t)(j + 1) * 4096;
      const bf16* Vg = Vg0 + (j + 1) * 64;
      r0 = *(const bf16x8*)(Kg + trow * 64 + tcol * 8);
      r1 = *(const bf16x8*)(Kg + (trow + 32) * 64 + tcol * 8);
      r2 = *(const bf16x8*)(Vg + (size_t)trow * 1024 + tcol * 8);
      r3 = *(const bf16x8*)(Vg + (size_t)(trow + 32) * 1024 + tcol * 8);
    }
    __syncthreads();

    if (j <= jdiag) {
      const bool diag = (j == jdiag);
      // S = relu(mask(Q K^T)) -> bf16 in LDS (wave-private rows)
#pragma unroll
      for (int ct = 0; ct < 4; ++ct) {
        bf16x8 kf0 = *(const bf16x8*)(bK + (ct * 16 + mn) * 144 + quad * 16);
        bf16x8 kf1 = *(const bf16x8*)(bK + (ct * 16 + mn) * 144 + 64 + quad * 16);
        int kkc = j * 64 + ct * 16 + mn;
#pragma unroll
        for (int i = 0; i < 2; ++i) {
          f32x4 a = {};
          a = __builtin_amdgcn_mfma_f32_16x16x32_bf16(qf[i][0], kf0, a, 0, 0, 0);
          a = __builtin_amdgcn_mfma_f32_16x16x32_bf16(qf[i][1], kf1, a, 0, 0, 0);
          int qr = q0 + wave * 32 + i * 16 + quad * 4;
#pragma unroll
          for (int r = 0; r < 4; ++r) {
            float v = a[r];
            v = v > 0.f ? v : 0.f;
            if (diag && kkc > qr + r) v = 0.f;
            ((bf16*)ldsS)[(wave * 32 + i * 16 + quad * 4 + r) * 72 + ct * 16 + mn] = (bf16)v;
          }
        }
      }
      // Y += S * V
#pragma unroll
      for (int kb = 0; kb < 2; ++kb) {
        bf16x8 vf[4];
#pragma unroll
        for (int ct = 0; ct < 4; ++ct)
          vf[ct] = *(const bf16x8*)(bV + (ct * 16 + mn) * 144 + kb * 64 + quad * 16);
#pragma unroll
        for (int i = 0; i < 2; ++i) {
          bf16x8 sf = *(const bf16x8*)(ldsS + (wave * 32 + i * 16 + mn) * 144 + kb * 64 + quad * 16);
#pragma unroll
          for (int ct = 0; ct < 4; ++ct)
            yacc[i][ct] = __builtin_amdgcn_mfma_f32_16x16x32_bf16(sf, vf[ct], yacc[i][ct], 0, 0, 0);
        }
      }
    }
  }

  // write out: out[b][t][h*64+d]
  const int b = bh / 12, h = bh % 12;
#pragma unroll
  for (int i = 0; i < 2; ++i) {
    float* ob = out + ((size_t)b * 1024 + q0 + wave * 32 + i * 16 + quad * 4) * 768 + h * 64;
#pragma unroll
    for (int ct = 0; ct < 4; ++ct)
#pragma unroll
      for (int r = 0; r < 4; ++r)
        ob[(size_t)r * 768 + ct * 16 + mn] = yacc[i][ct][r];
  }
}

// ---------------------------------------------------------------------------
extern "C" void kernel_launch(void* const* d_in, const int* in_sizes, int n_in,
                              void* d_out, int out_size, void* d_ws, size_t ws_size,
                              hipStream_t stream) {
  const float* x    = (const float*)d_in[0];   // [8,1024,768]
  const float* W    = (const float*)d_in[1];   // [768,2304]
  const float* bias = (const float*)d_in[2];   // [2304]
  float* out = (float*)d_out;                  // [8,1024,768]

  char* ws = (char*)d_ws;
  bf16* xb = (bf16*)(ws);                      // 8192*768        = 12,582,912 B
  bf16* Wt = (bf16*)(ws + 12582912);           // 2304*768        =  3,538,944 B
  bf16* Qb = (bf16*)(ws + 16121856);           // 96*1024*64
  bf16* Kb = (bf16*)(ws + 28704768);           // 96*1024*64
  bf16* Vb = (bf16*)(ws + 41287680);           // 96*64*1024 (V^T)

  convert_x_kernel<<<3072, 256, 0, stream>>>(x, xb);
  transpose_w_kernel<<<dim3(72, 24), dim3(32, 8), 0, stream>>>(W, Wt);
  qkv_gemm_kernel<<<dim3(18, 64), 256, 0, stream>>>(xb, Wt, bias, Qb, Kb, Vb);
  attn_kernel<<<dim3(96, 8), 256, 0, stream>>>(Qb, Kb, Vb, out);
}